// Round 9
// baseline (413.547 us; speedup 1.0000x reference)
//
#include <hip/hip_runtime.h>
#include <hip/hip_bf16.h>
#include <math.h>

#define N_NODES 50000
#define IN_DIM 256
#define HEADS 4
#define CDIM 64
#define HC 256        // HEADS*CDIM
#define HOPS 3
#define EDGES 400000
#define NEG_SLOPE 0.2f
#define SEG (EDGES + N_NODES)            // hop0 flat range incl self-loops
#define TOT_E (3 * EDGES + N_NODES)      // flat edge count across hops
#define CAP 40                           // bucket capacity; P(Poisson(8)+1 > 40) ~ 1e-16

// gemm tiling
#define TM 128
#define TN 128
#define TK 32
#define LDP 40
#define GEMM_BX  ((N_NODES + TM - 1) / TM)       // 391

// mega kernel block ranges: [gemm | gate | scatter]
#define NB_GEMM  (GEMM_BX * 4)                   // 1564 (512 out cols / 128)
#define NB_GATE  ((N_NODES + 3) / 4)             // 12500
#define NB_SCAT  ((TOT_E + 255) / 256)           // 4883

typedef unsigned short ushort;
using short8  = __attribute__((ext_vector_type(8))) short;
using floatx4 = __attribute__((ext_vector_type(4))) float;

// flat layout: hop0 [0, E+N) incl self-loops ; hop1 [SEG, SEG+E) ; hop2 [...]
__device__ __forceinline__ void decode_flat(int f, int& k, int& e)
{
    if (f < SEG)              { k = 0; e = f; }
    else if (f < SEG + EDGES) { k = 1; e = f - SEG; }
    else                      { k = 2; e = f - SEG - EDGES; }
}

__device__ __forceinline__ ushort f2bf(float f)
{
    unsigned u = __float_as_uint(f);
    unsigned r = u + 0x7fffu + ((u >> 16) & 1u);   // RNE
    return (ushort)(r >> 16);
}

// pack two fp32 -> bf16x2 (RNE), a in low 16 bits
__device__ __forceinline__ unsigned pk2(float a, float b)
{
    __hip_bfloat162 h = __float22bfloat162_rn(make_float2(a, b));
    union { __hip_bfloat162 h; unsigned u; } c;
    c.h = h;
    return c.u;
}

// ---------------------------------------------------------------------------
// mega: fused [GEMM (fp32 in, bf16 LDS staging, MFMA) | gate | bucket scatter]
// by blockIdx range. GEMM reads x / W_l / W_r fp32 directly, converts to bf16
// in-register -> no pack kernels, no Xb/WT buffers, scatter+gate latency
// hides under MFMA.
// ---------------------------------------------------------------------------
__global__ __launch_bounds__(256) void mega(
    const float* __restrict__ X,
    const float* __restrict__ Wl, const float* __restrict__ Wr,
    const float* __restrict__ b_l, const float* __restrict__ b_r,
    ushort* __restrict__ xlb, ushort* __restrict__ xrb, int M,
    const float* __restrict__ Wg, const float* __restrict__ bg,
    float* __restrict__ gw,
    const int* __restrict__ ei0, const int* __restrict__ ei1,
    const int* __restrict__ ei2, int* __restrict__ cnt,
    int* __restrict__ bucket)
{
    __shared__ ushort As[TM][LDP];
    __shared__ ushort Bs[TN][LDP];
    const int blk = blockIdx.x;
    const int tid = threadIdx.x;

    if (blk < NB_GEMM) {
        // ================= GEMM =================
        const int wave = tid >> 6, lane = tid & 63;
        const int row0 = (blk % GEMM_BX) * TM;
        const int col0 = (blk / GEMM_BX) * TN;       // 0,128,256,384
        const int wy = (wave >> 1) * 64, wx = (wave & 1) * 64;
        const int lrow = lane & 15, lk = (lane >> 4) * 8;

        // W source for this column tile (tile never straddles the 256 boundary)
        const bool left = (col0 < HC);
        const float* Wsrc = left ? (Wl + col0) : (Wr + col0 - HC);

        floatx4 acc[4][4];
        #pragma unroll
        for (int i = 0; i < 4; i++)
            #pragma unroll
            for (int j = 0; j < 4; j++)
                acc[i][j] = (floatx4){0.f, 0.f, 0.f, 0.f};

        for (int k0 = 0; k0 < IN_DIM; k0 += TK) {
            // ---- A tile: thread t -> row r=t>>1, 16 k at cb=(t&1)*16 ----
            {
                const int r  = tid >> 1;
                const int cb = (tid & 1) * 16;
                const int gr = row0 + r;
                float4 v0 = {0,0,0,0}, v1 = {0,0,0,0}, v2 = {0,0,0,0}, v3 = {0,0,0,0};
                if (gr < M) {
                    const float4* px = (const float4*)(X + (size_t)gr * IN_DIM + k0 + cb);
                    v0 = px[0]; v1 = px[1]; v2 = px[2]; v3 = px[3];
                }
                uint4 ua, ub;
                ua.x = pk2(v0.x, v0.y); ua.y = pk2(v0.z, v0.w);
                ua.z = pk2(v1.x, v1.y); ua.w = pk2(v1.z, v1.w);
                ub.x = pk2(v2.x, v2.y); ub.y = pk2(v2.z, v2.w);
                ub.z = pk2(v3.x, v3.y); ub.w = pk2(v3.z, v3.w);
                *(uint4*)&As[r][cb + 0] = ua;
                *(uint4*)&As[r][cb + 8] = ub;
            }
            // ---- B tile: thread t -> k-pair kp=t>>4, 8 n at nb=(t&15)*8 ----
            {
                const int kp = tid >> 4;          // 0..15
                const int nb = (tid & 15) * 8;    // 0..120
                const int kr = k0 + 2 * kp;
                const float* w0 = Wsrc + (size_t)kr * HC + nb;
                const float* w1 = w0 + HC;
                float4 a0 = *(const float4*)(w0 + 0);
                float4 a1 = *(const float4*)(w0 + 4);
                float4 b0 = *(const float4*)(w1 + 0);
                float4 b1 = *(const float4*)(w1 + 4);
                *(unsigned*)&Bs[nb + 0][2 * kp] = pk2(a0.x, b0.x);
                *(unsigned*)&Bs[nb + 1][2 * kp] = pk2(a0.y, b0.y);
                *(unsigned*)&Bs[nb + 2][2 * kp] = pk2(a0.z, b0.z);
                *(unsigned*)&Bs[nb + 3][2 * kp] = pk2(a0.w, b0.w);
                *(unsigned*)&Bs[nb + 4][2 * kp] = pk2(a1.x, b1.x);
                *(unsigned*)&Bs[nb + 5][2 * kp] = pk2(a1.y, b1.y);
                *(unsigned*)&Bs[nb + 6][2 * kp] = pk2(a1.z, b1.z);
                *(unsigned*)&Bs[nb + 7][2 * kp] = pk2(a1.w, b1.w);
            }
            __syncthreads();

            short8 af[4], bf[4];
            #pragma unroll
            for (int mi = 0; mi < 4; mi++)
                af[mi] = *(const short8*)&As[wy + mi * 16 + lrow][lk];
            #pragma unroll
            for (int ni = 0; ni < 4; ni++)
                bf[ni] = *(const short8*)&Bs[wx + ni * 16 + lrow][lk];

            // swapped operands -> lane holds row m=lane&15, cols consecutive
            #pragma unroll
            for (int mi = 0; mi < 4; mi++)
                #pragma unroll
                for (int ni = 0; ni < 4; ni++)
                    acc[mi][ni] = __builtin_amdgcn_mfma_f32_16x16x32_bf16(
                        bf[ni], af[mi], acc[mi][ni], 0, 0, 0);
            __syncthreads();
        }

        const int csub = (lane >> 4) * 4;
        ushort* dstbuf = left ? xlb : xrb;
        const float* bvec = left ? b_l : b_r;
        const int cbase = left ? col0 : col0 - HC;
        #pragma unroll
        for (int mi = 0; mi < 4; mi++) {
            int grow = row0 + wy + mi * 16 + lrow;
            if (grow < M) {
                #pragma unroll
                for (int ni = 0; ni < 4; ni++) {
                    int gcol = cbase + wx + ni * 16 + csub;
                    floatx4 v = acc[mi][ni];
                    const float4 b = *(const float4*)(bvec + gcol);
                    union { ushort s[4]; uint2 u; } o;
                    o.s[0] = f2bf(v[0] + b.x);
                    o.s[1] = f2bf(v[1] + b.y);
                    o.s[2] = f2bf(v[2] + b.z);
                    o.s[3] = f2bf(v[3] + b.w);
                    *(uint2*)(dstbuf + (size_t)grow * HC + gcol) = o.u;
                }
            }
        }
    } else if (blk < NB_GEMM + NB_GATE) {
        // ================= gate =================
        const int node = ((blk - NB_GEMM) * 256 + tid) >> 6;
        const int lane = tid & 63;
        if (node >= N_NODES) return;

        float4 xv = ((const float4*)(X + (size_t)node * IN_DIM))[lane];

        float a0 = 0.f, a1 = 0.f, a2 = 0.f;
        const int i0 = lane * 4;
        a0 += xv.x * Wg[(i0 + 0) * HOPS + 0]; a1 += xv.x * Wg[(i0 + 0) * HOPS + 1]; a2 += xv.x * Wg[(i0 + 0) * HOPS + 2];
        a0 += xv.y * Wg[(i0 + 1) * HOPS + 0]; a1 += xv.y * Wg[(i0 + 1) * HOPS + 1]; a2 += xv.y * Wg[(i0 + 1) * HOPS + 2];
        a0 += xv.z * Wg[(i0 + 2) * HOPS + 0]; a1 += xv.z * Wg[(i0 + 2) * HOPS + 1]; a2 += xv.z * Wg[(i0 + 2) * HOPS + 2];
        a0 += xv.w * Wg[(i0 + 3) * HOPS + 0]; a1 += xv.w * Wg[(i0 + 3) * HOPS + 1]; a2 += xv.w * Wg[(i0 + 3) * HOPS + 2];

        #pragma unroll
        for (int off = 32; off >= 1; off >>= 1) {
            a0 += __shfl_xor(a0, off);
            a1 += __shfl_xor(a1, off);
            a2 += __shfl_xor(a2, off);
        }
        if (lane == 0) {
            float l0 = a0 + bg[0], l1 = a1 + bg[1], l2 = a2 + bg[2];
            float m = fmaxf(l0, fmaxf(l1, l2));
            float e0 = expf(l0 - m), e1 = expf(l1 - m), e2 = expf(l2 - m);
            float inv = 1.f / (e0 + e1 + e2);
            gw[node * HOPS + 0] = e0 * inv;
            gw[node * HOPS + 1] = e1 * inv;
            gw[node * HOPS + 2] = e2 * inv;
        }
    } else {
        // ================= bucket scatter =================
        int f = (blk - NB_GEMM - NB_GATE) * 256 + tid;
        if (f >= TOT_E) return;
        int k, e; decode_flat(f, k, e);
        int s, d;
        if (k == 0 && e >= EDGES) { s = d = e - EDGES; }
        else {
            const int* ei = (k == 0) ? ei0 : (k == 1) ? ei1 : ei2;
            s = ei[e]; d = ei[EDGES + e];
        }
        int pos = atomicAdd(&cnt[k * N_NODES + d], 1);
        if (pos < CAP)
            bucket[((size_t)k * N_NODES + d) * CAP + pos] = s;
    }
}

// ---------------------------------------------------------------------------
// node_all: one 192-thread block (3 waves) per node; wave k = hop k.
// Two edges per iteration (32 lanes each, uint4 = 8 bf16 ch/lane), 1-pair
// prefetch, plain exp, halves merged xor-32, head-mean xor-8/16, gw+bias
// folded. Hop results combined through LDS; one non-atomic 256B store.
// ---------------------------------------------------------------------------
__global__ __launch_bounds__(192) void node_all(
    const ushort* __restrict__ xlb, const ushort* __restrict__ xrb,
    const int* __restrict__ cnt, const int* __restrict__ bucket,
    const float* __restrict__ att, const float* __restrict__ gw,
    const float* __restrict__ bias, float* __restrict__ out)
{
    __shared__ float lds[HOPS][CDIM];
    const int n    = blockIdx.x;
    const int k    = threadIdx.x >> 6;   // hop
    const int lane = threadIdx.x & 63;
    const int half = lane >> 5;          // which edge of the pair
    const int sub  = lane & 31;          // channel group: ch = sub*8 .. sub*8+7

    const int deg = min(cnt[k * N_NODES + n], CAP);
    const int* bk = bucket + ((size_t)k * N_NODES + n) * CAP;

    // xr channels for this lane (bf16 -> fp32)
    uint4 rq = *(const uint4*)(xrb + (size_t)n * HC + sub * 8);
    const float rr0 = __uint_as_float(rq.x << 16);
    const float rr1 = __uint_as_float(rq.x & 0xffff0000u);
    const float rr2 = __uint_as_float(rq.y << 16);
    const float rr3 = __uint_as_float(rq.y & 0xffff0000u);
    const float rr4 = __uint_as_float(rq.z << 16);
    const float rr5 = __uint_as_float(rq.z & 0xffff0000u);
    const float rr6 = __uint_as_float(rq.w << 16);
    const float rr7 = __uint_as_float(rq.w & 0xffff0000u);

    const float4 wa = ((const float4*)(att + (size_t)k * HC))[sub * 2 + 0];
    const float4 wb = ((const float4*)(att + (size_t)k * HC))[sub * 2 + 1];

    float denom = 0.f;
    float acc[8] = {0.f, 0.f, 0.f, 0.f, 0.f, 0.f, 0.f, 0.f};

    if (deg > 0) {
        int myS = bk[lane < deg ? lane : deg - 1];   // padded: lanes>=deg hold last
        const int npair = (deg + 1) >> 1;

        int s0 = __shfl(myS, half);
        uint4 q = *(const uint4*)(xlb + (size_t)s0 * HC + sub * 8);

        for (int j = 0; j < npair; j++) {
            int idxn = 2 * (j + 1) + half;           // <= 41 < 64; padded myS valid
            int sn = __shfl(myS, idxn);
            uint4 qn = *(const uint4*)(xlb + (size_t)sn * HC + sub * 8);

            float f0 = __uint_as_float(q.x << 16);
            float f1 = __uint_as_float(q.x & 0xffff0000u);
            float f2 = __uint_as_float(q.y << 16);
            float f3 = __uint_as_float(q.y & 0xffff0000u);
            float f4 = __uint_as_float(q.z << 16);
            float f5 = __uint_as_float(q.z & 0xffff0000u);
            float f6 = __uint_as_float(q.w << 16);
            float f7 = __uint_as_float(q.w & 0xffff0000u);

            float v0 = f0 + rr0, v1 = f1 + rr1, v2 = f2 + rr2, v3 = f3 + rr3;
            float v4 = f4 + rr4, v5 = f5 + rr5, v6 = f6 + rr6, v7 = f7 + rr7;

            // lrelu(v)*w = (0.6*w)*v + (0.4*w)*|v|
            float p;
            p = 0.6f * wa.x * v0 + 0.4f * wa.x * fabsf(v0);
            p = fmaf(0.6f * wa.y, v1, p); p = fmaf(0.4f * wa.y, fabsf(v1), p);
            p = fmaf(0.6f * wa.z, v2, p); p = fmaf(0.4f * wa.z, fabsf(v2), p);
            p = fmaf(0.6f * wa.w, v3, p); p = fmaf(0.4f * wa.w, fabsf(v3), p);
            p = fmaf(0.6f * wb.x, v4, p); p = fmaf(0.4f * wb.x, fabsf(v4), p);
            p = fmaf(0.6f * wb.y, v5, p); p = fmaf(0.4f * wb.y, fabsf(v5), p);
            p = fmaf(0.6f * wb.z, v6, p); p = fmaf(0.4f * wb.z, fabsf(v6), p);
            p = fmaf(0.6f * wb.w, v7, p); p = fmaf(0.4f * wb.w, fabsf(v7), p);

            // per-head reduce: head = 8 consecutive lanes (within half)
            p += __shfl_xor(p, 1);
            p += __shfl_xor(p, 2);
            p += __shfl_xor(p, 4);

            bool valid = (2 * j + half) < deg;
            float ex = valid ? __expf(p) : 0.f;
            denom += ex;
            acc[0] = fmaf(ex, f0, acc[0]);
            acc[1] = fmaf(ex, f1, acc[1]);
            acc[2] = fmaf(ex, f2, acc[2]);
            acc[3] = fmaf(ex, f3, acc[3]);
            acc[4] = fmaf(ex, f4, acc[4]);
            acc[5] = fmaf(ex, f5, acc[5]);
            acc[6] = fmaf(ex, f6, acc[6]);
            acc[7] = fmaf(ex, f7, acc[7]);
            q = qn;
        }
    }

    // merge the two halves (same channels, different edge subsets)
    denom += __shfl_xor(denom, 32);
    #pragma unroll
    for (int i = 0; i < 8; i++) acc[i] += __shfl_xor(acc[i], 32);

    float inv = (denom > 0.f) ? 1.f / denom : 0.f;
    const float g  = gw[n * HOPS + k];
    const float* bb = bias + (size_t)k * CDIM + (sub & 7) * 8;

    #pragma unroll
    for (int i = 0; i < 8; i++) {
        float v = acc[i] * inv;
        // head mean: sum lanes {sub&7, +8, +16, +24}
        v += __shfl_xor(v, 8);
        v += __shfl_xor(v, 16);
        if (lane < 8) lds[k][lane * 8 + i] = g * (v * 0.25f + bb[i]);
    }
    __syncthreads();

    if (threadIdx.x < CDIM)
        out[(size_t)n * CDIM + threadIdx.x] =
            lds[0][threadIdx.x] + lds[1][threadIdx.x] + lds[2][threadIdx.x];
}

// ---------------------------------------------------------------------------
extern "C" void kernel_launch(void* const* d_in, const int* in_sizes, int n_in,
                              void* d_out, int out_size, void* d_ws, size_t ws_size,
                              hipStream_t stream)
{
    const float* x      = (const float*)d_in[0];
    const int*   ei0    = (const int*)d_in[1];
    const int*   ei1    = (const int*)d_in[2];
    const int*   ei2    = (const int*)d_in[3];
    const float* W_l    = (const float*)d_in[4];
    const float* b_l    = (const float*)d_in[5];
    const float* W_r    = (const float*)d_in[6];
    const float* b_r    = (const float*)d_in[7];
    const float* att    = (const float*)d_in[8];   // [3,4,64]
    const float* bias   = (const float*)d_in[9];   // [3,64]
    const float* W_gate = (const float*)d_in[10];  // [256,3]
    const float* b_gate = (const float*)d_in[11];  // [3]

    const size_t NHC = (size_t)N_NODES * HC;       // 12,800,000
    float* ws      = (float*)d_ws;
    float* gwbuf   = ws;                           // 150,000
    int*   cnt     = (int*)(gwbuf + HOPS * N_NODES);         // 150,000
    int*   bucket  = cnt + HOPS * N_NODES;         // 3*N*CAP = 6,000,000
    ushort* xlb    = (ushort*)(bucket + (size_t)HOPS * N_NODES * CAP); // NHC bf16
    ushort* xrb    = xlb + NHC;                    // NHC bf16

    hipMemsetAsync(cnt, 0, (size_t)HOPS * N_NODES * sizeof(int), stream);

    // fused [GEMM(conv-in-reg) | gate | bucket scatter]
    mega<<<NB_GEMM + NB_GATE + NB_SCAT, 256, 0, stream>>>(
        x, W_l, W_r, b_l, b_r, xlb, xrb, N_NODES,
        W_gate, b_gate, gwbuf, ei0, ei1, ei2, cnt, bucket);

    // fused logits + softmax + aggregate + head-mean + gate combine
    node_all<<<N_NODES, 192, 0, stream>>>(
        xlb, xrb, cnt, bucket, att, gwbuf, bias, (float*)d_out);
}

// Round 10
// 404.667 us; speedup vs baseline: 1.0219x; 1.0219x over previous
//
#include <hip/hip_runtime.h>
#include <hip/hip_bf16.h>
#include <math.h>

#define N_NODES 50000
#define IN_DIM 256
#define HEADS 4
#define CDIM 64
#define HC 256        // HEADS*CDIM
#define HOPS 3
#define EDGES 400000
#define NEG_SLOPE 0.2f
#define SEG (EDGES + N_NODES)            // hop0 flat range incl self-loops
#define TOT_E (3 * EDGES + N_NODES)      // flat edge count across hops
#define CAP 40                           // bucket capacity; P(Poisson(8)+1 > 40) ~ 1e-16

// gemm tiling
#define TM 128
#define TN 128
#define TK 32
#define LDP 40
#define GEMM_BX  ((N_NODES + TM - 1) / TM)       // 391

// mega2 block ranges: [gemm | gate | scatter]
#define NB_GEMM  (GEMM_BX * 4)                   // 1564 (512 out cols / 128)
#define NB_GATE  ((N_NODES + 3) / 4)             // 12500
#define NB_SCAT  ((TOT_E + 255) / 256)           // 4883

typedef unsigned short ushort;
using short8  = __attribute__((ext_vector_type(8))) short;
using floatx4 = __attribute__((ext_vector_type(4))) float;

// flat layout: hop0 [0, E+N) incl self-loops ; hop1 [SEG, SEG+E) ; hop2 [...]
__device__ __forceinline__ void decode_flat(int f, int& k, int& e)
{
    if (f < SEG)              { k = 0; e = f; }
    else if (f < SEG + EDGES) { k = 1; e = f - SEG; }
    else                      { k = 2; e = f - SEG - EDGES; }
}

__device__ __forceinline__ ushort f2bf(float f)
{
    unsigned u = __float_as_uint(f);
    unsigned r = u + 0x7fffu + ((u >> 16) & 1u);   // RNE
    return (ushort)(r >> 16);
}

// pack two fp32 -> bf16x2 (RNE), a in low 16 bits
__device__ __forceinline__ unsigned pk2(float a, float b)
{
    __hip_bfloat162 h = __float22bfloat162_rn(make_float2(a, b));
    union { __hip_bfloat162 h; unsigned u; } c;
    c.h = h;
    return c.u;
}

// ---------------------------------------------------------------------------
// pack_w: WT[n][k] = bf16( n<256 ? W_l[k][n] : W_r[k][n-256] ). [512][256].
// Writes coalesced along k; reads are strided but W is 512KB (L2-resident).
// ---------------------------------------------------------------------------
__global__ __launch_bounds__(256) void pack_w(const float* __restrict__ Wl,
                                              const float* __restrict__ Wr,
                                              ushort* __restrict__ WT)
{
    int id = blockIdx.x * 256 + threadIdx.x;        // 131072 threads
    int n = id >> 8;            // 0..511
    int k = id & 255;           // 0..255
    float v = (n < HC) ? Wl[k * HC + n] : Wr[k * HC + (n - HC)];
    WT[(size_t)n * IN_DIM + k] = f2bf(v);
}

// ---------------------------------------------------------------------------
// mega2: fused [GEMM | gate | bucket scatter] by blockIdx range.
// GEMM: A-operand read from fp32 x directly with in-register bf16 convert
// (16B LDS writes, benign conflict level); B-operand from pre-packed WT
// (R8's conflict-free staging). Gate + scatter latency hides under MFMA.
// ---------------------------------------------------------------------------
__global__ __launch_bounds__(256) void mega2(
    const float* __restrict__ X, const ushort* __restrict__ WT,
    const float* __restrict__ b_l, const float* __restrict__ b_r,
    ushort* __restrict__ xlb, ushort* __restrict__ xrb, int M,
    const float* __restrict__ Wg, const float* __restrict__ bg,
    float* __restrict__ gw,
    const int* __restrict__ ei0, const int* __restrict__ ei1,
    const int* __restrict__ ei2, int* __restrict__ cnt,
    int* __restrict__ bucket)
{
    __shared__ ushort As[TM][LDP];
    __shared__ ushort Bs[TN][LDP];
    const int blk = blockIdx.x;
    const int tid = threadIdx.x;

    if (blk < NB_GEMM) {
        // ================= GEMM =================
        const int wave = tid >> 6, lane = tid & 63;
        const int row0 = (blk % GEMM_BX) * TM;
        const int col0 = (blk / GEMM_BX) * TN;       // 0,128,256,384
        const int wy = (wave >> 1) * 64, wx = (wave & 1) * 64;
        const int lrow = lane & 15, lk = (lane >> 4) * 8;

        floatx4 acc[4][4];
        #pragma unroll
        for (int i = 0; i < 4; i++)
            #pragma unroll
            for (int j = 0; j < 4; j++)
                acc[i][j] = (floatx4){0.f, 0.f, 0.f, 0.f};

        // A-load indices: thread t -> row r=t>>1, 16 k at cb=(t&1)*16
        const int ar = tid >> 1;
        const int acb = (tid & 1) * 16;
        const int agr = row0 + ar;

        for (int k0 = 0; k0 < IN_DIM; k0 += TK) {
            // ---- A tile from fp32 x, convert in-register ----
            {
                float4 v0 = {0,0,0,0}, v1 = {0,0,0,0}, v2 = {0,0,0,0}, v3 = {0,0,0,0};
                if (agr < M) {
                    const float4* px = (const float4*)(X + (size_t)agr * IN_DIM + k0 + acb);
                    v0 = px[0]; v1 = px[1]; v2 = px[2]; v3 = px[3];
                }
                uint4 ua, ub;
                ua.x = pk2(v0.x, v0.y); ua.y = pk2(v0.z, v0.w);
                ua.z = pk2(v1.x, v1.y); ua.w = pk2(v1.z, v1.w);
                ub.x = pk2(v2.x, v2.y); ub.y = pk2(v2.z, v2.w);
                ub.z = pk2(v3.x, v3.y); ub.w = pk2(v3.z, v3.w);
                *(uint4*)&As[ar][acb + 0] = ua;
                *(uint4*)&As[ar][acb + 8] = ub;
            }
            // ---- B tile from WT (already [n][k] bf16) ----
            #pragma unroll
            for (int j = 0; j < 2; j++) {
                int id = tid + 256 * j;
                int r  = id >> 2;
                int c  = (id & 3) * 8;
                *(uint4*)&Bs[r][c] =
                    *(const uint4*)(WT + (size_t)(col0 + r) * IN_DIM + k0 + c);
            }
            __syncthreads();

            short8 af[4], bf[4];
            #pragma unroll
            for (int mi = 0; mi < 4; mi++)
                af[mi] = *(const short8*)&As[wy + mi * 16 + lrow][lk];
            #pragma unroll
            for (int ni = 0; ni < 4; ni++)
                bf[ni] = *(const short8*)&Bs[wx + ni * 16 + lrow][lk];

            // swapped operands -> lane holds row m=lane&15, cols consecutive
            #pragma unroll
            for (int mi = 0; mi < 4; mi++)
                #pragma unroll
                for (int ni = 0; ni < 4; ni++)
                    acc[mi][ni] = __builtin_amdgcn_mfma_f32_16x16x32_bf16(
                        bf[ni], af[mi], acc[mi][ni], 0, 0, 0);
            __syncthreads();
        }

        const bool left = (col0 < HC);
        const int csub = (lane >> 4) * 4;
        ushort* dstbuf = left ? xlb : xrb;
        const float* bvec = left ? b_l : b_r;
        const int cbase = left ? col0 : col0 - HC;
        #pragma unroll
        for (int mi = 0; mi < 4; mi++) {
            int grow = row0 + wy + mi * 16 + lrow;
            if (grow < M) {
                #pragma unroll
                for (int ni = 0; ni < 4; ni++) {
                    int gcol = cbase + wx + ni * 16 + csub;
                    floatx4 v = acc[mi][ni];
                    const float4 b = *(const float4*)(bvec + gcol);
                    union { ushort s[4]; uint2 u; } o;
                    o.s[0] = f2bf(v[0] + b.x);
                    o.s[1] = f2bf(v[1] + b.y);
                    o.s[2] = f2bf(v[2] + b.z);
                    o.s[3] = f2bf(v[3] + b.w);
                    *(uint2*)(dstbuf + (size_t)grow * HC + gcol) = o.u;
                }
            }
        }
    } else if (blk < NB_GEMM + NB_GATE) {
        // ================= gate =================
        const int node = ((blk - NB_GEMM) * 256 + tid) >> 6;
        const int lane = tid & 63;
        if (node >= N_NODES) return;

        float4 xv = ((const float4*)(X + (size_t)node * IN_DIM))[lane];

        float a0 = 0.f, a1 = 0.f, a2 = 0.f;
        const int i0 = lane * 4;
        a0 += xv.x * Wg[(i0 + 0) * HOPS + 0]; a1 += xv.x * Wg[(i0 + 0) * HOPS + 1]; a2 += xv.x * Wg[(i0 + 0) * HOPS + 2];
        a0 += xv.y * Wg[(i0 + 1) * HOPS + 0]; a1 += xv.y * Wg[(i0 + 1) * HOPS + 1]; a2 += xv.y * Wg[(i0 + 1) * HOPS + 2];
        a0 += xv.z * Wg[(i0 + 2) * HOPS + 0]; a1 += xv.z * Wg[(i0 + 2) * HOPS + 1]; a2 += xv.z * Wg[(i0 + 2) * HOPS + 2];
        a0 += xv.w * Wg[(i0 + 3) * HOPS + 0]; a1 += xv.w * Wg[(i0 + 3) * HOPS + 1]; a2 += xv.w * Wg[(i0 + 3) * HOPS + 2];

        #pragma unroll
        for (int off = 32; off >= 1; off >>= 1) {
            a0 += __shfl_xor(a0, off);
            a1 += __shfl_xor(a1, off);
            a2 += __shfl_xor(a2, off);
        }
        if (lane == 0) {
            float l0 = a0 + bg[0], l1 = a1 + bg[1], l2 = a2 + bg[2];
            float m = fmaxf(l0, fmaxf(l1, l2));
            float e0 = expf(l0 - m), e1 = expf(l1 - m), e2 = expf(l2 - m);
            float inv = 1.f / (e0 + e1 + e2);
            gw[node * HOPS + 0] = e0 * inv;
            gw[node * HOPS + 1] = e1 * inv;
            gw[node * HOPS + 2] = e2 * inv;
        }
    } else {
        // ================= bucket scatter =================
        int f = (blk - NB_GEMM - NB_GATE) * 256 + tid;
        if (f >= TOT_E) return;
        int k, e; decode_flat(f, k, e);
        int s, d;
        if (k == 0 && e >= EDGES) { s = d = e - EDGES; }
        else {
            const int* ei = (k == 0) ? ei0 : (k == 1) ? ei1 : ei2;
            s = ei[e]; d = ei[EDGES + e];
        }
        int pos = atomicAdd(&cnt[k * N_NODES + d], 1);
        if (pos < CAP)
            bucket[((size_t)k * N_NODES + d) * CAP + pos] = s;
    }
}

// ---------------------------------------------------------------------------
// node_all: one 192-thread block (3 waves) per node; wave k = hop k.
// Two edges per iteration (32 lanes each, uint4 = 8 bf16 ch/lane), 1-pair
// prefetch, plain exp, halves merged xor-32, head-mean xor-8/16, gw+bias
// folded. Hop results combined through LDS; one non-atomic 256B store.
// (Frozen: runs at ~94% of the ~2 TB/s random-gather L2-fill ceiling.)
// ---------------------------------------------------------------------------
__global__ __launch_bounds__(192) void node_all(
    const ushort* __restrict__ xlb, const ushort* __restrict__ xrb,
    const int* __restrict__ cnt, const int* __restrict__ bucket,
    const float* __restrict__ att, const float* __restrict__ gw,
    const float* __restrict__ bias, float* __restrict__ out)
{
    __shared__ float lds[HOPS][CDIM];
    const int n    = blockIdx.x;
    const int k    = threadIdx.x >> 6;   // hop
    const int lane = threadIdx.x & 63;
    const int half = lane >> 5;          // which edge of the pair
    const int sub  = lane & 31;          // channel group: ch = sub*8 .. sub*8+7

    const int deg = min(cnt[k * N_NODES + n], CAP);
    const int* bk = bucket + ((size_t)k * N_NODES + n) * CAP;

    // xr channels for this lane (bf16 -> fp32)
    uint4 rq = *(const uint4*)(xrb + (size_t)n * HC + sub * 8);
    const float rr0 = __uint_as_float(rq.x << 16);
    const float rr1 = __uint_as_float(rq.x & 0xffff0000u);
    const float rr2 = __uint_as_float(rq.y << 16);
    const float rr3 = __uint_as_float(rq.y & 0xffff0000u);
    const float rr4 = __uint_as_float(rq.z << 16);
    const float rr5 = __uint_as_float(rq.z & 0xffff0000u);
    const float rr6 = __uint_as_float(rq.w << 16);
    const float rr7 = __uint_as_float(rq.w & 0xffff0000u);

    const float4 wa = ((const float4*)(att + (size_t)k * HC))[sub * 2 + 0];
    const float4 wb = ((const float4*)(att + (size_t)k * HC))[sub * 2 + 1];

    float denom = 0.f;
    float acc[8] = {0.f, 0.f, 0.f, 0.f, 0.f, 0.f, 0.f, 0.f};

    if (deg > 0) {
        int myS = bk[lane < deg ? lane : deg - 1];   // padded: lanes>=deg hold last
        const int npair = (deg + 1) >> 1;

        int s0 = __shfl(myS, half);
        uint4 q = *(const uint4*)(xlb + (size_t)s0 * HC + sub * 8);

        for (int j = 0; j < npair; j++) {
            int idxn = 2 * (j + 1) + half;           // <= 41 < 64; padded myS valid
            int sn = __shfl(myS, idxn);
            uint4 qn = *(const uint4*)(xlb + (size_t)sn * HC + sub * 8);

            float f0 = __uint_as_float(q.x << 16);
            float f1 = __uint_as_float(q.x & 0xffff0000u);
            float f2 = __uint_as_float(q.y << 16);
            float f3 = __uint_as_float(q.y & 0xffff0000u);
            float f4 = __uint_as_float(q.z << 16);
            float f5 = __uint_as_float(q.z & 0xffff0000u);
            float f6 = __uint_as_float(q.w << 16);
            float f7 = __uint_as_float(q.w & 0xffff0000u);

            float v0 = f0 + rr0, v1 = f1 + rr1, v2 = f2 + rr2, v3 = f3 + rr3;
            float v4 = f4 + rr4, v5 = f5 + rr5, v6 = f6 + rr6, v7 = f7 + rr7;

            // lrelu(v)*w = (0.6*w)*v + (0.4*w)*|v|  (abs folds into fma modifier)
            float p;
            p = 0.6f * wa.x * v0 + 0.4f * wa.x * fabsf(v0);
            p = fmaf(0.6f * wa.y, v1, p); p = fmaf(0.4f * wa.y, fabsf(v1), p);
            p = fmaf(0.6f * wa.z, v2, p); p = fmaf(0.4f * wa.z, fabsf(v2), p);
            p = fmaf(0.6f * wa.w, v3, p); p = fmaf(0.4f * wa.w, fabsf(v3), p);
            p = fmaf(0.6f * wb.x, v4, p); p = fmaf(0.4f * wb.x, fabsf(v4), p);
            p = fmaf(0.6f * wb.y, v5, p); p = fmaf(0.4f * wb.y, fabsf(v5), p);
            p = fmaf(0.6f * wb.z, v6, p); p = fmaf(0.4f * wb.z, fabsf(v6), p);
            p = fmaf(0.6f * wb.w, v7, p); p = fmaf(0.4f * wb.w, fabsf(v7), p);

            // per-head reduce: head = 8 consecutive lanes (within half)
            p += __shfl_xor(p, 1);
            p += __shfl_xor(p, 2);
            p += __shfl_xor(p, 4);

            bool valid = (2 * j + half) < deg;
            float ex = valid ? __expf(p) : 0.f;
            denom += ex;
            acc[0] = fmaf(ex, f0, acc[0]);
            acc[1] = fmaf(ex, f1, acc[1]);
            acc[2] = fmaf(ex, f2, acc[2]);
            acc[3] = fmaf(ex, f3, acc[3]);
            acc[4] = fmaf(ex, f4, acc[4]);
            acc[5] = fmaf(ex, f5, acc[5]);
            acc[6] = fmaf(ex, f6, acc[6]);
            acc[7] = fmaf(ex, f7, acc[7]);
            q = qn;
        }
    }

    // merge the two halves (same channels, different edge subsets)
    denom += __shfl_xor(denom, 32);
    #pragma unroll
    for (int i = 0; i < 8; i++) acc[i] += __shfl_xor(acc[i], 32);

    float inv = (denom > 0.f) ? 1.f / denom : 0.f;
    const float g  = gw[n * HOPS + k];
    const float* bb = bias + (size_t)k * CDIM + (sub & 7) * 8;

    #pragma unroll
    for (int i = 0; i < 8; i++) {
        float v = acc[i] * inv;
        // head mean: sum lanes {sub&7, +8, +16, +24}
        v += __shfl_xor(v, 8);
        v += __shfl_xor(v, 16);
        if (lane < 8) lds[k][lane * 8 + i] = g * (v * 0.25f + bb[i]);
    }
    __syncthreads();

    if (threadIdx.x < CDIM)
        out[(size_t)n * CDIM + threadIdx.x] =
            lds[0][threadIdx.x] + lds[1][threadIdx.x] + lds[2][threadIdx.x];
}

// ---------------------------------------------------------------------------
extern "C" void kernel_launch(void* const* d_in, const int* in_sizes, int n_in,
                              void* d_out, int out_size, void* d_ws, size_t ws_size,
                              hipStream_t stream)
{
    const float* x      = (const float*)d_in[0];
    const int*   ei0    = (const int*)d_in[1];
    const int*   ei1    = (const int*)d_in[2];
    const int*   ei2    = (const int*)d_in[3];
    const float* W_l    = (const float*)d_in[4];
    const float* b_l    = (const float*)d_in[5];
    const float* W_r    = (const float*)d_in[6];
    const float* b_r    = (const float*)d_in[7];
    const float* att    = (const float*)d_in[8];   // [3,4,64]
    const float* bias   = (const float*)d_in[9];   // [3,64]
    const float* W_gate = (const float*)d_in[10];  // [256,3]
    const float* b_gate = (const float*)d_in[11];  // [3]

    const size_t NHC = (size_t)N_NODES * HC;       // 12,800,000
    float* ws      = (float*)d_ws;
    float* gwbuf   = ws;                           // 150,000
    int*   cnt     = (int*)(gwbuf + HOPS * N_NODES);         // 150,000
    int*   bucket  = cnt + HOPS * N_NODES;         // 3*N*CAP = 6,000,000
    ushort* xlb    = (ushort*)(bucket + (size_t)HOPS * N_NODES * CAP); // NHC bf16
    ushort* xrb    = xlb + NHC;                    // NHC bf16
    ushort* WT     = xrb + NHC;                    // 131,072 bf16

    hipMemsetAsync(cnt, 0, (size_t)HOPS * N_NODES * sizeof(int), stream);

    // W transpose+pack once (tiny; conflict-free consumer staging)
    pack_w<<<(IN_DIM * 2 * HC) / 256, 256, 0, stream>>>(W_l, W_r, WT);

    // fused [GEMM (x fp32 direct, in-reg bf16 cvt) | gate | bucket scatter]
    mega2<<<NB_GEMM + NB_GATE + NB_SCAT, 256, 0, stream>>>(
        x, WT, b_l, b_r, xlb, xrb, N_NODES,
        W_gate, b_gate, gwbuf, ei0, ei1, ei2, cnt, bucket);

    // fused logits + softmax + aggregate + head-mean + gate combine
    node_all<<<N_NODES, 192, 0, stream>>>(
        xlb, xrb, cnt, bucket, att, gwbuf, bias, (float*)d_out);
}